// Round 10
// baseline (208.796 us; speedup 1.0000x reference)
//
#include <hip/hip_runtime.h>
#include <math.h>

#define S_LEN 1024
#define DMODEL 1024

typedef __attribute__((ext_vector_type(8))) short bf16x8;
typedef __attribute__((ext_vector_type(4))) short bf16x4;
typedef __attribute__((ext_vector_type(4))) float f32x4;

#define MFMA16(a, b, c) __builtin_amdgcn_mfma_f32_16x16x32_bf16(a, b, c, 0, 0, 0)

#define WP (1024u * 1024u)       // W plane, ushorts (2 MB)
#define XP (4u * 1024u * 1024u)  // X/head plane, ushorts (8 MB)

// Ph row stride (ushorts): 76 not 72 -> quad*4-row spacing maps to distinct
// banks ((2*76*4/4)%32 = 24 -> offsets {0,24,16,8}), killing the 4-way
// write conflict measured at stride 72 (3.69M conflict cycles, R8).
#define PH_S 76

// round-to-nearest-even fp32 -> bf16
__device__ __forceinline__ unsigned short rne_bf16(float f) {
    unsigned u = __float_as_uint(f);
    u += 0x7FFFu + ((u >> 16) & 1u);
    return (unsigned short)(u >> 16);
}

// split fp32 -> bf16 hi (RNE) + bf16 lo (RNE residual)
__device__ __forceinline__ void split_rne(float f, unsigned short& h, unsigned short& l) {
    unsigned short hh = rne_bf16(f);
    float lf = f - __uint_as_float(((unsigned)hh) << 16);
    h = hh;
    l = rne_bf16(lf);
}

// async global->LDS, 16B per lane. LDS dest = wave-uniform base + lane*16.
typedef const __attribute__((address_space(1))) unsigned int* gas_t;
typedef __attribute__((address_space(3))) unsigned int* las_t;
__device__ __forceinline__ void glds16(const void* g, void* l) {
    __builtin_amdgcn_global_load_lds((gas_t)g, (las_t)l, 16, 0, 0);
}

// ---------------------------------------------------------------------------
// Converter: Wq/Wk/Wv -> rne-hi plane; Wo -> hi+lo planes; query/key/value
// fp32 -> rne bf16 planes. blocks 0..4095 = W, 4096..16383 = X.
// Masked-row elimination for k/v planes (mask monotone per batch):
// fully-masked proj tile -> skip row entirely; partial tile -> zero-fill.
// ---------------------------------------------------------------------------
__global__ __launch_bounds__(256)
void convert_wx(const float* __restrict__ W0, const float* __restrict__ W1,
                const float* __restrict__ W2, const float* __restrict__ W3,
                const float* __restrict__ Xq, const float* __restrict__ Xk,
                const float* __restrict__ Xv, const int* __restrict__ mask,
                unsigned short* __restrict__ Wpl, unsigned short* __restrict__ Xbase) {
    int blk = blockIdx.x;
    if (blk < 4096) {
        const int which = blk >> 10;
        const float* W = which == 0 ? W0 : which == 1 ? W1 : which == 2 ? W2 : W3;
        int i = ((blk & 1023) * 256 + threadIdx.x) * 4;
        float4 f = *(const float4*)&W[i];
        if (which == 3) {
            unsigned short* hi = Wpl + 3 * WP;
            unsigned short* lo = Wpl + 4 * WP;
            bf16x4 h, l;
            unsigned short hh, ll;
            split_rne(f.x, hh, ll); h[0] = (short)hh; l[0] = (short)ll;
            split_rne(f.y, hh, ll); h[1] = (short)hh; l[1] = (short)ll;
            split_rne(f.z, hh, ll); h[2] = (short)hh; l[2] = (short)ll;
            split_rne(f.w, hh, ll); h[3] = (short)hh; l[3] = (short)ll;
            *(bf16x4*)&hi[i] = h;
            *(bf16x4*)&lo[i] = l;
        } else {
            unsigned short* hi = Wpl + (size_t)which * WP;
            bf16x4 h;
            h[0] = (short)rne_bf16(f.x);
            h[1] = (short)rne_bf16(f.y);
            h[2] = (short)rne_bf16(f.z);
            h[3] = (short)rne_bf16(f.w);
            *(bf16x4*)&hi[i] = h;
        }
    } else {
        blk -= 4096;
        const int which = blk >> 12;  // 0=q 1=k 2=v
        const float* X = which == 0 ? Xq : which == 1 ? Xk : Xv;
        unsigned short* Xr = Xbase + (size_t)which * XP;
        int i = ((blk & 4095) * 256 + threadIdx.x) * 4;
        if (which != 0) {
            const int b = i >> 20, s = (i >> 10) & 1023;
            if (mask[b * 1024 + s]) {
                if (mask[b * 1024 + (s & ~127)]) return;  // tile skipped by proj
                bf16x4 zz = {0, 0, 0, 0};
                *(bf16x4*)&Xr[i] = zz;                    // partial tile: zero-fill
                return;
            }
        }
        float4 f = *(const float4*)&X[i];
        bf16x4 h;
        h[0] = (short)rne_bf16(f.x);
        h[1] = (short)rne_bf16(f.y);
        h[2] = (short)rne_bf16(f.z);
        h[3] = (short)rne_bf16(f.w);
        *(bf16x4*)&Xr[i] = h;
    }
}

// ---------------------------------------------------------------------------
// Fused Q/K/V projection: z picks {Q,K,V}. C = Xr * W^T.
// 128x128 tile, BK=64 as TWO [128][32] halves with the proven 64B-row
// layout + XOR chunk swizzle (2-way-only LDS reads, 0 conflicts).
// Per kt: stage both halves (8 glds16/wave), ONE barrier pair, 32 MFMA.
// T1 XCD swizzle; mask skip for fully-masked K/V tiles.
// NEW: z=0 epilogue folds the softmax scale 0.125*log2(e) into Q so attn
// can use exp2 directly (removes 16 v_mul/lane/tile from its hot loop).
// Epilogue: z=0/1 rne -> [b][h][s][dh]; z=2 rne -> [b][h][dh][s] (8B stores).
// ---------------------------------------------------------------------------
__global__ __launch_bounds__(256)
void gemm_proj(const unsigned short* __restrict__ Xbase,
               const unsigned short* __restrict__ Wpl,
               const int* __restrict__ mask,
               unsigned short* __restrict__ Obase) {
    __shared__ unsigned short AS[2][128 * 32];
    __shared__ unsigned short BS[2][128 * 32];

    const int z = blockIdx.z;
    const unsigned short* A = Xbase + (size_t)z * XP;
    const unsigned short* B = Wpl + (size_t)z * WP;

    const int t = threadIdx.x, lane = t & 63, w = t >> 6;
    const int quad = lane >> 4, l15 = lane & 15;
    const int wr = w & 1, wc = w >> 1;

    // XCD-aware bijective swizzle over the 256 blocks of this z-plane.
    const int linb = blockIdx.x + (blockIdx.y << 3);      // [0,256)
    const int swz = ((linb & 7) << 5) + (linb >> 3);
    const int bx = swz & 7, by = swz >> 3;
    const int rowBase = by * 128, colBase = bx * 128;

    // K/V tiles with all rows masked are dead downstream.
    if (z && mask[(by >> 3) * 1024 + ((by & 7) << 7)]) return;

    // staging addresses: inst e covers tile rows [w*32+e*16, +16); +32 u16
    // moves to the second 32-K half of the same BK=64 step.
    const unsigned short* gA[2];
    const unsigned short* gB[2];
    #pragma unroll
    for (int e = 0; e < 2; e++) {
        int row = w * 32 + e * 16 + (lane >> 2);
        int cg = (lane & 3) ^ ((row >> 1) & 3);   // global chunk for this lane's LDS slot
        gA[e] = A + (size_t)(rowBase + row) * 1024 + cg * 8;
        gB[e] = B + (size_t)(colBase + row) * 1024 + cg * 8;
    }
    const int ldA0 = (w * 32) * 32, ldA1 = (w * 32 + 16) * 32;  // wave-uniform dests

    // fragment LDS addresses within a [128][32] half (constant over K-loop)
    int aAd[4], bAd[4];
    #pragma unroll
    for (int i = 0; i < 4; i++) {
        int ra = wr * 64 + i * 16 + l15;
        aAd[i] = ra * 32 + (quad ^ ((ra >> 1) & 3)) * 8;
        int rb = wc * 64 + i * 16 + l15;
        bAd[i] = rb * 32 + (quad ^ ((rb >> 1) & 3)) * 8;
    }

    f32x4 acc[4][4] = {};

    for (int kt = 0; kt < 16; kt++) {
        if (kt) __syncthreads();          // prior MFMA reads done before overwrite
        const int ko = kt * 64;
        glds16(gA[0] + ko,      &AS[0][ldA0]);
        glds16(gA[1] + ko,      &AS[0][ldA1]);
        glds16(gB[0] + ko,      &BS[0][ldA0]);
        glds16(gB[1] + ko,      &BS[0][ldA1]);
        glds16(gA[0] + ko + 32, &AS[1][ldA0]);
        glds16(gA[1] + ko + 32, &AS[1][ldA1]);
        glds16(gB[0] + ko + 32, &BS[1][ldA0]);
        glds16(gB[1] + ko + 32, &BS[1][ldA1]);
        __syncthreads();                  // compiler: vmcnt(0) drain + barrier

        #pragma unroll
        for (int h2 = 0; h2 < 2; h2++) {
            bf16x8 af[4], bfr[4];
            #pragma unroll
            for (int i = 0; i < 4; i++) af[i] = *(const bf16x8*)&AS[h2][aAd[i]];
            #pragma unroll
            for (int j = 0; j < 4; j++) bfr[j] = *(const bf16x8*)&BS[h2][bAd[j]];
            #pragma unroll
            for (int j = 0; j < 4; j++)
                #pragma unroll
                for (int i = 0; i < 4; i++)
                    acc[i][j] = MFMA16(af[i], bfr[j], acc[i][j]);
        }
    }

    // z=0: fold softmax scale into Q (exact fp32 mul before bf16 rounding)
    const float qs = (z == 0) ? 0.18033688011f : 1.0f;  // 0.125*log2(e)

    unsigned short* O = Obase + (size_t)z * XP;
    #pragma unroll
    for (int i = 0; i < 4; i++)
        #pragma unroll
        for (int j = 0; j < 4; j++) {
            const int m0 = rowBase + wr * 64 + i * 16 + quad * 4;  // 4 consec s, no batch cross
            const int n = colBase + wc * 64 + j * 16 + l15;
            const int bb = m0 >> 10, s = m0 & 1023, hh = n >> 6, dh = n & 63;
            const size_t hb = ((size_t)(bb * 16 + hh)) << 16;
            if (z == 2) {
                bf16x4 v4;
                #pragma unroll
                for (int r = 0; r < 4; r++) v4[r] = (short)rne_bf16(acc[i][j][r]);
                *(bf16x4*)&O[hb + (size_t)dh * 1024 + s] = v4;
            } else {
                #pragma unroll
                for (int r = 0; r < 4; r++)
                    O[hb + (size_t)(s + r) * 64 + dh] = rne_bf16(acc[i][j][r] * qs);
            }
        }
}

// ---------------------------------------------------------------------------
// Output projection: C = WSr * Wo^T, 2 MFMA passes (Wo hi+lo), fp32 out.
// 128x64 tile, BK=64 (two 32-K halves). LDS 32KB. Grid (16,32), T1 swizzle.
// (R8's 128x128/48KB variant regressed ~11us -> this is the structure of
//  record.)
// ---------------------------------------------------------------------------
__global__ __launch_bounds__(256)
void gemm_out2(const unsigned short* __restrict__ A,
               const unsigned short* __restrict__ Bh, const unsigned short* __restrict__ Bl,
               float* __restrict__ Cf) {
    __shared__ unsigned short AS[2][128 * 32];
    __shared__ unsigned short BhS[2][64 * 32], BlS[2][64 * 32];

    const int t = threadIdx.x, lane = t & 63, w = t >> 6;
    const int quad = lane >> 4, l15 = lane & 15;
    const int wr = w & 1, wc = w >> 1;

    const int linb = blockIdx.x + (blockIdx.y << 4);      // [0,512)
    const int swz = ((linb & 7) << 6) + (linb >> 3);
    const int bx = swz & 15, by = swz >> 4;
    const int rowBase = by * 128, colBase = bx * 64;

    const unsigned short* gA[2];
    #pragma unroll
    for (int e = 0; e < 2; e++) {
        int row = w * 32 + e * 16 + (lane >> 2);
        int cg = (lane & 3) ^ ((row >> 1) & 3);
        gA[e] = A + (size_t)(rowBase + row) * 1024 + cg * 8;
    }
    const unsigned short *gBh, *gBl;
    {
        int row = w * 16 + (lane >> 2);
        int cg = (lane & 3) ^ ((row >> 1) & 3);
        gBh = Bh + (size_t)(colBase + row) * 1024 + cg * 8;
        gBl = Bl + (size_t)(colBase + row) * 1024 + cg * 8;
    }
    const int ldA0 = (w * 32) * 32, ldA1 = (w * 32 + 16) * 32;
    const int ldB = (w * 16) * 32;

    int aAd[4], bAd[2];
    #pragma unroll
    for (int i = 0; i < 4; i++) {
        int ra = wr * 64 + i * 16 + l15;
        aAd[i] = ra * 32 + (quad ^ ((ra >> 1) & 3)) * 8;
    }
    #pragma unroll
    for (int j = 0; j < 2; j++) {
        int rb = wc * 32 + j * 16 + l15;
        bAd[j] = rb * 32 + (quad ^ ((rb >> 1) & 3)) * 8;
    }

    f32x4 acc[4][2] = {};

    for (int kt = 0; kt < 16; kt++) {
        if (kt) __syncthreads();
        const int ko = kt * 64;
        glds16(gA[0] + ko,      &AS[0][ldA0]);
        glds16(gA[1] + ko,      &AS[0][ldA1]);
        glds16(gBh + ko,        &BhS[0][ldB]);
        glds16(gBl + ko,        &BlS[0][ldB]);
        glds16(gA[0] + ko + 32, &AS[1][ldA0]);
        glds16(gA[1] + ko + 32, &AS[1][ldA1]);
        glds16(gBh + ko + 32,   &BhS[1][ldB]);
        glds16(gBl + ko + 32,   &BlS[1][ldB]);
        __syncthreads();

        #pragma unroll
        for (int h2 = 0; h2 < 2; h2++) {
            bf16x8 af[4], bhf[2], blf[2];
            #pragma unroll
            for (int i = 0; i < 4; i++) af[i] = *(const bf16x8*)&AS[h2][aAd[i]];
            #pragma unroll
            for (int j = 0; j < 2; j++) {
                bhf[j] = *(const bf16x8*)&BhS[h2][bAd[j]];
                blf[j] = *(const bf16x8*)&BlS[h2][bAd[j]];
            }
            #pragma unroll
            for (int j = 0; j < 2; j++)
                #pragma unroll
                for (int i = 0; i < 4; i++) {
                    acc[i][j] = MFMA16(af[i], bhf[j], acc[i][j]);
                    acc[i][j] = MFMA16(af[i], blf[j], acc[i][j]);
                }
        }
    }

    #pragma unroll
    for (int i = 0; i < 4; i++)
        #pragma unroll
        for (int j = 0; j < 2; j++)
            #pragma unroll
            for (int r = 0; r < 4; r++) {
                int m = rowBase + wr * 64 + i * 16 + quad * 4 + r;
                int n = colBase + wc * 32 + j * 16 + l15;
                Cf[(size_t)m * 1024 + n] = acc[i][j][r];
            }
}

// ---------------------------------------------------------------------------
// Flash attention, no-max softmax (bounded scores), single-plane rne Q/K/V.
// Single-buffered K/V (R9's dbuf cut occupancy 4->3 blocks/CU and regressed
// 10us -> occupancy > barrier count here). Ph stride 76 (bank-conflict fix);
// Q pre-scaled by 0.125*log2(e) in proj -> p = exp2(s) directly.
// T1 XCD swizzle; T14 async-STAGE split; T5 setprio. LDS 32.2 KB.
// ---------------------------------------------------------------------------
__global__ __launch_bounds__(256)
void attn_mfma(const unsigned short* __restrict__ Qr, const unsigned short* __restrict__ Kr,
               const unsigned short* __restrict__ Vt,
               const int* __restrict__ mask, const float* __restrict__ gamma,
               unsigned short* __restrict__ WSr) {
    __shared__ int maskS[1024];
    __shared__ unsigned short Ks[64 * 72];         // [j][d]
    __shared__ unsigned short Vs[64 * 72];         // [d][j]
    __shared__ unsigned short Ph[4 * 16 * PH_S];   // per-wave [q][j], stride 76

    const int t = threadIdx.x, lane = t & 63, w = t >> 6;
    const int quad = lane >> 4, l15 = lane & 15;

    const int linb = blockIdx.x + (blockIdx.y << 4);      // [0,256) per batch
    const int swz = ((linb & 7) << 5) + (linb >> 3);
    const int qx = swz & 15, h = swz >> 4;

    const int q0 = qx * 64, b = blockIdx.z;
    const size_t hb = ((size_t)(b * 16 + h)) << 16;

    ((int4*)maskS)[t] = ((const int4*)(mask + b * 1024))[t];

    bf16x8 qhi[2];
    {
        const int qrow = q0 + w * 16 + l15;
        const size_t qb = hb + (size_t)qrow * 64 + quad * 8;
        qhi[0] = *(const bf16x8*)&Qr[qb];
        qhi[1] = *(const bf16x8*)&Qr[qb + 32];
    }

    // staging geometry: thread covers (row = e*32 + t>>3, chunk c = t&7)
    const int sc = (t & 7) * 8;
    const int sr = t >> 3;

    f32x4 o[4] = {};
    float lsum[4] = {0.f, 0.f, 0.f, 0.f};

    // prologue: stage tile 0 (lengths >= 512 so tile 0 is never fully masked)
    bf16x8 kreg[2], vreg[2];
    #pragma unroll
    for (int e = 0; e < 2; e++) {
        int row = e * 32 + sr;
        kreg[e] = *(const bf16x8*)&Kr[hb + (size_t)row * 64 + sc];
        vreg[e] = *(const bf16x8*)&Vt[hb + (size_t)row * 1024 + sc];
    }
    __syncthreads();   // maskS visible
    #pragma unroll
    for (int e = 0; e < 2; e++) {
        int row = e * 32 + sr;
        *(bf16x8*)&Ks[row * 72 + sc] = kreg[e];
        *(bf16x8*)&Vs[row * 72 + sc] = vreg[e];
    }
    __syncthreads();   // tile 0 staged

    for (int jt = 0; jt < 16; jt++) {
        const int j0 = jt * 64;
        if (maskS[j0]) break;
        const bool partial = maskS[j0 + 63] != 0;
        const int j0n = j0 + 64;
        const bool pf = (jt < 15) && (maskS[j0n] == 0);  // block-uniform

        // T14: issue next tile's global loads NOW; used only after the barrier
        if (pf) {
            #pragma unroll
            for (int e = 0; e < 2; e++) {
                int row = e * 32 + sr;
                kreg[e] = *(const bf16x8*)&Kr[hb + (size_t)(j0n + row) * 64 + sc];
                vreg[e] = *(const bf16x8*)&Vt[hb + (size_t)row * 1024 + j0n + sc];
            }
        }

        f32x4 s4[4] = {};
        __builtin_amdgcn_s_setprio(1);
        #pragma unroll
        for (int nj = 0; nj < 4; nj++) {
            int kr = (nj * 16 + l15) * 72 + quad * 8;
            #pragma unroll
            for (int kk = 0; kk < 2; kk++) {
                bf16x8 kv = *(const bf16x8*)&Ks[kr + kk * 32];
                s4[nj] = MFMA16(qhi[kk], kv, s4[nj]);
            }
        }
        __builtin_amdgcn_s_setprio(0);

        if (partial) {
            #pragma unroll
            for (int nj = 0; nj < 4; nj++) {
                int mk = maskS[j0 + nj * 16 + l15];
                #pragma unroll
                for (int r = 0; r < 4; r++) {
                    float p = mk ? 0.f : exp2f(s4[nj][r]);
                    lsum[r] += p;
                    Ph[(w * 16 + quad * 4 + r) * PH_S + nj * 16 + l15] = rne_bf16(p);
                }
            }
        } else {
            #pragma unroll
            for (int nj = 0; nj < 4; nj++) {
                #pragma unroll
                for (int r = 0; r < 4; r++) {
                    float p = exp2f(s4[nj][r]);
                    lsum[r] += p;
                    Ph[(w * 16 + quad * 4 + r) * PH_S + nj * 16 + l15] = rne_bf16(p);
                }
            }
        }

        bf16x8 ph[2];
        #pragma unroll
        for (int ks = 0; ks < 2; ks++)
            ph[ks] = *(const bf16x8*)&Ph[(w * 16 + l15) * PH_S + ks * 32 + quad * 8];
        __builtin_amdgcn_s_setprio(1);
        #pragma unroll
        for (int dt = 0; dt < 4; dt++) {
            int vr = (dt * 16 + l15) * 72 + quad * 8;
            #pragma unroll
            for (int ks = 0; ks < 2; ks++) {
                bf16x8 vv = *(const bf16x8*)&Vs[vr + ks * 32];
                o[dt] = MFMA16(ph[ks], vv, o[dt]);
            }
        }
        __builtin_amdgcn_s_setprio(0);

        if (pf) {
            __syncthreads();   // all waves done reading Ks/Vs
            #pragma unroll
            for (int e = 0; e < 2; e++) {
                int row = e * 32 + sr;
                *(bf16x8*)&Ks[row * 72 + sc] = kreg[e];   // compiler waits vmcnt here
                *(bf16x8*)&Vs[row * 72 + sc] = vreg[e];
            }
            __syncthreads();   // next tile staged
        }
    }

    #pragma unroll
    for (int r = 0; r < 4; r++) {
        lsum[r] += __shfl_xor(lsum[r], 1);
        lsum[r] += __shfl_xor(lsum[r], 2);
        lsum[r] += __shfl_xor(lsum[r], 4);
        lsum[r] += __shfl_xor(lsum[r], 8);
    }

    const float g = gamma[h];
    #pragma unroll
    for (int r = 0; r < 4; r++) {
        const int qrow = q0 + w * 16 + quad * 4 + r;
        const float sc2 = g / lsum[r];
        const size_t base = ((size_t)b * 1024 + qrow) * 1024 + h * 64;
        #pragma unroll
        for (int dt = 0; dt < 4; dt++)
            WSr[base + dt * 16 + l15] = rne_bf16(o[dt][r] * sc2);
    }
}

// ---------------------------------------------------------------------------
extern "C" void kernel_launch(void* const* d_in, const int* in_sizes, int n_in,
                              void* d_out, int out_size, void* d_ws, size_t ws_size,
                              hipStream_t stream) {
    const float* query = (const float*)d_in[0];
    const float* key   = (const float*)d_in[1];
    const float* value = (const float*)d_in[2];
    const int*   mask  = (const int*)d_in[3];
    const float* Wq    = (const float*)d_in[4];
    const float* Wk    = (const float*)d_in[5];
    const float* Wv    = (const float*)d_in[6];
    const float* Wo    = (const float*)d_in[7];
    const float* gamma = (const float*)d_in[8];
    float* out = (float*)d_out;

    unsigned short* u = (unsigned short*)d_ws;
    // 58 MB layout (29M ushorts):
    unsigned short* Xbase = u;          // Xqr, Xkr, Xvr (3 x XP)
    unsigned short* Obase = u + 3 * XP; // Qr, Kr, Vt (3 x XP)
    unsigned short* Wpl   = u + 6 * XP; // Wqh, Wkh, Wvh, Woh, Wol (5 x WP)
    unsigned short* WSr   = Xbase;      // alias: Xqr dead after gemm_proj
    unsigned short* Qr = Obase, *Kr = Obase + XP, *Vt = Obase + 2 * XP;
    unsigned short* Woh = Wpl + 3 * WP, *Wol = Wpl + 4 * WP;

    convert_wx<<<16384, 256, 0, stream>>>(Wq, Wk, Wv, Wo, query, key, value, mask, Wpl, Xbase);

    gemm_proj<<<dim3(8, 32, 3), 256, 0, stream>>>(Xbase, Wpl, mask, Obase);

    attn_mfma<<<dim3(16, 16, 4), 256, 0, stream>>>(Qr, Kr, Vt, mask, gamma, WSr);

    gemm_out2<<<dim3(16, 32), 256, 0, stream>>>(WSr, Woh, Wol, out);
}

// Round 11
// 197.363 us; speedup vs baseline: 1.0579x; 1.0579x over previous
//
#include <hip/hip_runtime.h>
#include <math.h>

#define S_LEN 1024
#define DMODEL 1024

typedef __attribute__((ext_vector_type(8))) short bf16x8;
typedef __attribute__((ext_vector_type(4))) short bf16x4;
typedef __attribute__((ext_vector_type(4))) float f32x4;

#define MFMA16(a, b, c) __builtin_amdgcn_mfma_f32_16x16x32_bf16(a, b, c, 0, 0, 0)

#define WP (1024u * 1024u)       // W plane, ushorts (2 MB)
#define XP (4u * 1024u * 1024u)  // X/head plane, ushorts (8 MB)

// round-to-nearest-even fp32 -> bf16
__device__ __forceinline__ unsigned short rne_bf16(float f) {
    unsigned u = __float_as_uint(f);
    u += 0x7FFFu + ((u >> 16) & 1u);
    return (unsigned short)(u >> 16);
}

// split fp32 -> bf16 hi (RNE) + bf16 lo (RNE residual)
__device__ __forceinline__ void split_rne(float f, unsigned short& h, unsigned short& l) {
    unsigned short hh = rne_bf16(f);
    float lf = f - __uint_as_float(((unsigned)hh) << 16);
    h = hh;
    l = rne_bf16(lf);
}

// async global->LDS, 16B per lane. LDS dest = wave-uniform base + lane*16.
typedef const __attribute__((address_space(1))) unsigned int* gas_t;
typedef __attribute__((address_space(3))) unsigned int* las_t;
__device__ __forceinline__ void glds16(const void* g, void* l) {
    __builtin_amdgcn_global_load_lds((gas_t)g, (las_t)l, 16, 0, 0);
}

// ---------------------------------------------------------------------------
// Converter: Wq/Wk/Wv -> rne-hi plane; Wo -> hi+lo planes; query/key/value
// fp32 -> rne bf16 planes. blocks 0..4095 = W, 4096..16383 = X.
// Masked-row elimination for k/v planes (mask monotone per batch):
// fully-masked proj tile -> skip row entirely; partial tile -> zero-fill.
// ---------------------------------------------------------------------------
__global__ __launch_bounds__(256)
void convert_wx(const float* __restrict__ W0, const float* __restrict__ W1,
                const float* __restrict__ W2, const float* __restrict__ W3,
                const float* __restrict__ Xq, const float* __restrict__ Xk,
                const float* __restrict__ Xv, const int* __restrict__ mask,
                unsigned short* __restrict__ Wpl, unsigned short* __restrict__ Xbase) {
    int blk = blockIdx.x;
    if (blk < 4096) {
        const int which = blk >> 10;
        const float* W = which == 0 ? W0 : which == 1 ? W1 : which == 2 ? W2 : W3;
        int i = ((blk & 1023) * 256 + threadIdx.x) * 4;
        float4 f = *(const float4*)&W[i];
        if (which == 3) {
            unsigned short* hi = Wpl + 3 * WP;
            unsigned short* lo = Wpl + 4 * WP;
            bf16x4 h, l;
            unsigned short hh, ll;
            split_rne(f.x, hh, ll); h[0] = (short)hh; l[0] = (short)ll;
            split_rne(f.y, hh, ll); h[1] = (short)hh; l[1] = (short)ll;
            split_rne(f.z, hh, ll); h[2] = (short)hh; l[2] = (short)ll;
            split_rne(f.w, hh, ll); h[3] = (short)hh; l[3] = (short)ll;
            *(bf16x4*)&hi[i] = h;
            *(bf16x4*)&lo[i] = l;
        } else {
            unsigned short* hi = Wpl + (size_t)which * WP;
            bf16x4 h;
            h[0] = (short)rne_bf16(f.x);
            h[1] = (short)rne_bf16(f.y);
            h[2] = (short)rne_bf16(f.z);
            h[3] = (short)rne_bf16(f.w);
            *(bf16x4*)&hi[i] = h;
        }
    } else {
        blk -= 4096;
        const int which = blk >> 12;  // 0=q 1=k 2=v
        const float* X = which == 0 ? Xq : which == 1 ? Xk : Xv;
        unsigned short* Xr = Xbase + (size_t)which * XP;
        int i = ((blk & 4095) * 256 + threadIdx.x) * 4;
        if (which != 0) {
            const int b = i >> 20, s = (i >> 10) & 1023;
            if (mask[b * 1024 + s]) {
                if (mask[b * 1024 + (s & ~127)]) return;  // tile skipped by proj
                bf16x4 zz = {0, 0, 0, 0};
                *(bf16x4*)&Xr[i] = zz;                    // partial tile: zero-fill
                return;
            }
        }
        float4 f = *(const float4*)&X[i];
        bf16x4 h;
        h[0] = (short)rne_bf16(f.x);
        h[1] = (short)rne_bf16(f.y);
        h[2] = (short)rne_bf16(f.z);
        h[3] = (short)rne_bf16(f.w);
        *(bf16x4*)&Xr[i] = h;
    }
}

// ---------------------------------------------------------------------------
// Fused Q/K/V projection: z picks {Q,K,V}. C = Xr * W^T.
// 128x128 tile, BK=64 as TWO [128][32] halves with the proven 64B-row
// layout + XOR chunk swizzle (2-way-only LDS reads, 0 conflicts).
// Per kt: stage both halves (8 glds16/wave), ONE barrier pair, 32 MFMA.
// T1 XCD swizzle; mask skip for fully-masked K/V tiles.
// Epilogue: z=0/1 rne -> [b][h][s][dh]; z=2 rne -> [b][h][dh][s] (8B stores).
// ---------------------------------------------------------------------------
__global__ __launch_bounds__(256)
void gemm_proj(const unsigned short* __restrict__ Xbase,
               const unsigned short* __restrict__ Wpl,
               const int* __restrict__ mask,
               unsigned short* __restrict__ Obase) {
    __shared__ unsigned short AS[2][128 * 32];
    __shared__ unsigned short BS[2][128 * 32];

    const int z = blockIdx.z;
    const unsigned short* A = Xbase + (size_t)z * XP;
    const unsigned short* B = Wpl + (size_t)z * WP;

    const int t = threadIdx.x, lane = t & 63, w = t >> 6;
    const int quad = lane >> 4, l15 = lane & 15;
    const int wr = w & 1, wc = w >> 1;

    // XCD-aware bijective swizzle over the 256 blocks of this z-plane.
    const int linb = blockIdx.x + (blockIdx.y << 3);      // [0,256)
    const int swz = ((linb & 7) << 5) + (linb >> 3);
    const int bx = swz & 7, by = swz >> 3;
    const int rowBase = by * 128, colBase = bx * 128;

    // K/V tiles with all rows masked are dead downstream.
    if (z && mask[(by >> 3) * 1024 + ((by & 7) << 7)]) return;

    // staging addresses: inst e covers tile rows [w*32+e*16, +16); +32 u16
    // moves to the second 32-K half of the same BK=64 step.
    const unsigned short* gA[2];
    const unsigned short* gB[2];
    #pragma unroll
    for (int e = 0; e < 2; e++) {
        int row = w * 32 + e * 16 + (lane >> 2);
        int cg = (lane & 3) ^ ((row >> 1) & 3);   // global chunk for this lane's LDS slot
        gA[e] = A + (size_t)(rowBase + row) * 1024 + cg * 8;
        gB[e] = B + (size_t)(colBase + row) * 1024 + cg * 8;
    }
    const int ldA0 = (w * 32) * 32, ldA1 = (w * 32 + 16) * 32;  // wave-uniform dests

    // fragment LDS addresses within a [128][32] half (constant over K-loop)
    int aAd[4], bAd[4];
    #pragma unroll
    for (int i = 0; i < 4; i++) {
        int ra = wr * 64 + i * 16 + l15;
        aAd[i] = ra * 32 + (quad ^ ((ra >> 1) & 3)) * 8;
        int rb = wc * 64 + i * 16 + l15;
        bAd[i] = rb * 32 + (quad ^ ((rb >> 1) & 3)) * 8;
    }

    f32x4 acc[4][4] = {};

    for (int kt = 0; kt < 16; kt++) {
        if (kt) __syncthreads();          // prior MFMA reads done before overwrite
        const int ko = kt * 64;
        glds16(gA[0] + ko,      &AS[0][ldA0]);
        glds16(gA[1] + ko,      &AS[0][ldA1]);
        glds16(gB[0] + ko,      &BS[0][ldA0]);
        glds16(gB[1] + ko,      &BS[0][ldA1]);
        glds16(gA[0] + ko + 32, &AS[1][ldA0]);
        glds16(gA[1] + ko + 32, &AS[1][ldA1]);
        glds16(gB[0] + ko + 32, &BS[1][ldA0]);
        glds16(gB[1] + ko + 32, &BS[1][ldA1]);
        __syncthreads();                  // compiler: vmcnt(0) drain + barrier

        #pragma unroll
        for (int h2 = 0; h2 < 2; h2++) {
            bf16x8 af[4], bfr[4];
            #pragma unroll
            for (int i = 0; i < 4; i++) af[i] = *(const bf16x8*)&AS[h2][aAd[i]];
            #pragma unroll
            for (int j = 0; j < 4; j++) bfr[j] = *(const bf16x8*)&BS[h2][bAd[j]];
            #pragma unroll
            for (int j = 0; j < 4; j++)
                #pragma unroll
                for (int i = 0; i < 4; i++)
                    acc[i][j] = MFMA16(af[i], bfr[j], acc[i][j]);
        }
    }

    unsigned short* O = Obase + (size_t)z * XP;
    #pragma unroll
    for (int i = 0; i < 4; i++)
        #pragma unroll
        for (int j = 0; j < 4; j++) {
            const int m0 = rowBase + wr * 64 + i * 16 + quad * 4;  // 4 consec s, no batch cross
            const int n = colBase + wc * 64 + j * 16 + l15;
            const int bb = m0 >> 10, s = m0 & 1023, hh = n >> 6, dh = n & 63;
            const size_t hb = ((size_t)(bb * 16 + hh)) << 16;
            if (z == 2) {
                bf16x4 v4;
                #pragma unroll
                for (int r = 0; r < 4; r++) v4[r] = (short)rne_bf16(acc[i][j][r]);
                *(bf16x4*)&O[hb + (size_t)dh * 1024 + s] = v4;
            } else {
                #pragma unroll
                for (int r = 0; r < 4; r++)
                    O[hb + (size_t)(s + r) * 64 + dh] = rne_bf16(acc[i][j][r]);
            }
        }
}

// ---------------------------------------------------------------------------
// Output projection: C = WSr * Wo^T, 2 MFMA passes (Wo hi+lo), fp32 out.
// 128x64 tile, BK=64 (two 32-K halves). LDS 32KB. Grid (16,32), T1 swizzle.
// ---------------------------------------------------------------------------
__global__ __launch_bounds__(256)
void gemm_out2(const unsigned short* __restrict__ A,
               const unsigned short* __restrict__ Bh, const unsigned short* __restrict__ Bl,
               float* __restrict__ Cf) {
    __shared__ unsigned short AS[2][128 * 32];
    __shared__ unsigned short BhS[2][64 * 32], BlS[2][64 * 32];

    const int t = threadIdx.x, lane = t & 63, w = t >> 6;
    const int quad = lane >> 4, l15 = lane & 15;
    const int wr = w & 1, wc = w >> 1;

    const int linb = blockIdx.x + (blockIdx.y << 4);      // [0,512)
    const int swz = ((linb & 7) << 6) + (linb >> 3);
    const int bx = swz & 15, by = swz >> 4;
    const int rowBase = by * 128, colBase = bx * 64;

    const unsigned short* gA[2];
    #pragma unroll
    for (int e = 0; e < 2; e++) {
        int row = w * 32 + e * 16 + (lane >> 2);
        int cg = (lane & 3) ^ ((row >> 1) & 3);
        gA[e] = A + (size_t)(rowBase + row) * 1024 + cg * 8;
    }
    const unsigned short *gBh, *gBl;
    {
        int row = w * 16 + (lane >> 2);
        int cg = (lane & 3) ^ ((row >> 1) & 3);
        gBh = Bh + (size_t)(colBase + row) * 1024 + cg * 8;
        gBl = Bl + (size_t)(colBase + row) * 1024 + cg * 8;
    }
    const int ldA0 = (w * 32) * 32, ldA1 = (w * 32 + 16) * 32;
    const int ldB = (w * 16) * 32;

    int aAd[4], bAd[2];
    #pragma unroll
    for (int i = 0; i < 4; i++) {
        int ra = wr * 64 + i * 16 + l15;
        aAd[i] = ra * 32 + (quad ^ ((ra >> 1) & 3)) * 8;
    }
    #pragma unroll
    for (int j = 0; j < 2; j++) {
        int rb = wc * 32 + j * 16 + l15;
        bAd[j] = rb * 32 + (quad ^ ((rb >> 1) & 3)) * 8;
    }

    f32x4 acc[4][2] = {};

    for (int kt = 0; kt < 16; kt++) {
        if (kt) __syncthreads();
        const int ko = kt * 64;
        glds16(gA[0] + ko,      &AS[0][ldA0]);
        glds16(gA[1] + ko,      &AS[0][ldA1]);
        glds16(gBh + ko,        &BhS[0][ldB]);
        glds16(gBl + ko,        &BlS[0][ldB]);
        glds16(gA[0] + ko + 32, &AS[1][ldA0]);
        glds16(gA[1] + ko + 32, &AS[1][ldA1]);
        glds16(gBh + ko + 32,   &BhS[1][ldB]);
        glds16(gBl + ko + 32,   &BlS[1][ldB]);
        __syncthreads();

        #pragma unroll
        for (int h2 = 0; h2 < 2; h2++) {
            bf16x8 af[4], bhf[2], blf[2];
            #pragma unroll
            for (int i = 0; i < 4; i++) af[i] = *(const bf16x8*)&AS[h2][aAd[i]];
            #pragma unroll
            for (int j = 0; j < 2; j++) {
                bhf[j] = *(const bf16x8*)&BhS[h2][bAd[j]];
                blf[j] = *(const bf16x8*)&BlS[h2][bAd[j]];
            }
            #pragma unroll
            for (int j = 0; j < 2; j++)
                #pragma unroll
                for (int i = 0; i < 4; i++) {
                    acc[i][j] = MFMA16(af[i], bhf[j], acc[i][j]);
                    acc[i][j] = MFMA16(af[i], blf[j], acc[i][j]);
                }
        }
    }

    #pragma unroll
    for (int i = 0; i < 4; i++)
        #pragma unroll
        for (int j = 0; j < 2; j++)
            #pragma unroll
            for (int r = 0; r < 4; r++) {
                int m = rowBase + wr * 64 + i * 16 + quad * 4 + r;
                int n = colBase + wc * 32 + j * 16 + l15;
                Cf[(size_t)m * 1024 + n] = acc[i][j][r];
            }
}

// ---------------------------------------------------------------------------
// Flash attention, no-max softmax (bounded scores), single-plane rne Q/K/V.
// T1 XCD swizzle within each batch-plane; T14 async-STAGE split; T5 setprio.
// Single-buffered K/V, Ph stride 72, __expf — this EXACT source measured
// 41.7us / VGPR 52 / occ 32% (R8). R9 dbuf (occ 4->3) and R10 micro-edits
// (VGPR 52->68) each cost ~10us: do not perturb without a VGPR check.
// ---------------------------------------------------------------------------
__global__ __launch_bounds__(256)
void attn_mfma(const unsigned short* __restrict__ Qr, const unsigned short* __restrict__ Kr,
               const unsigned short* __restrict__ Vt,
               const int* __restrict__ mask, const float* __restrict__ gamma,
               unsigned short* __restrict__ WSr) {
    __shared__ int maskS[1024];
    __shared__ unsigned short Ks[64 * 72];      // [j][d]
    __shared__ unsigned short Vs[64 * 72];      // [d][j]
    __shared__ unsigned short Ph[4 * 16 * 72];  // per-wave [q][j]

    const int t = threadIdx.x, lane = t & 63, w = t >> 6;
    const int quad = lane >> 4, l15 = lane & 15;

    const int linb = blockIdx.x + (blockIdx.y << 4);      // [0,256) per batch
    const int swz = ((linb & 7) << 5) + (linb >> 3);
    const int qx = swz & 15, h = swz >> 4;

    const int q0 = qx * 64, b = blockIdx.z;
    const size_t hb = ((size_t)(b * 16 + h)) << 16;

    ((int4*)maskS)[t] = ((const int4*)(mask + b * 1024))[t];

    bf16x8 qhi[2];
    {
        const int qrow = q0 + w * 16 + l15;
        const size_t qb = hb + (size_t)qrow * 64 + quad * 8;
        qhi[0] = *(const bf16x8*)&Qr[qb];
        qhi[1] = *(const bf16x8*)&Qr[qb + 32];
    }

    // staging geometry: thread covers (row = e*32 + t>>3, chunk c = t&7)
    const int sc = (t & 7) * 8;
    const int sr = t >> 3;

    f32x4 o[4] = {};
    float lsum[4] = {0.f, 0.f, 0.f, 0.f};

    // prologue: stage tile 0 (lengths >= 512 so tile 0 is never fully masked)
    bf16x8 kreg[2], vreg[2];
    #pragma unroll
    for (int e = 0; e < 2; e++) {
        int row = e * 32 + sr;
        kreg[e] = *(const bf16x8*)&Kr[hb + (size_t)row * 64 + sc];
        vreg[e] = *(const bf16x8*)&Vt[hb + (size_t)row * 1024 + sc];
    }
    __syncthreads();   // maskS visible
    #pragma unroll
    for (int e = 0; e < 2; e++) {
        int row = e * 32 + sr;
        *(bf16x8*)&Ks[row * 72 + sc] = kreg[e];
        *(bf16x8*)&Vs[row * 72 + sc] = vreg[e];
    }
    __syncthreads();   // tile 0 staged

    for (int jt = 0; jt < 16; jt++) {
        const int j0 = jt * 64;
        if (maskS[j0]) break;
        const bool partial = maskS[j0 + 63] != 0;
        const int j0n = j0 + 64;
        const bool pf = (jt < 15) && (maskS[j0n] == 0);  // block-uniform

        // T14: issue next tile's global loads NOW; used only after the barrier
        if (pf) {
            #pragma unroll
            for (int e = 0; e < 2; e++) {
                int row = e * 32 + sr;
                kreg[e] = *(const bf16x8*)&Kr[hb + (size_t)(j0n + row) * 64 + sc];
                vreg[e] = *(const bf16x8*)&Vt[hb + (size_t)row * 1024 + j0n + sc];
            }
        }

        f32x4 s4[4] = {};
        __builtin_amdgcn_s_setprio(1);
        #pragma unroll
        for (int nj = 0; nj < 4; nj++) {
            int kr = (nj * 16 + l15) * 72 + quad * 8;
            #pragma unroll
            for (int kk = 0; kk < 2; kk++) {
                bf16x8 kv = *(const bf16x8*)&Ks[kr + kk * 32];
                s4[nj] = MFMA16(qhi[kk], kv, s4[nj]);
            }
        }
        __builtin_amdgcn_s_setprio(0);

        if (partial) {
            #pragma unroll
            for (int nj = 0; nj < 4; nj++) {
                int mk = maskS[j0 + nj * 16 + l15];
                #pragma unroll
                for (int r = 0; r < 4; r++) {
                    float p = mk ? 0.f : __expf(s4[nj][r] * 0.125f);
                    lsum[r] += p;
                    Ph[(w * 16 + quad * 4 + r) * 72 + nj * 16 + l15] = rne_bf16(p);
                }
            }
        } else {
            #pragma unroll
            for (int nj = 0; nj < 4; nj++) {
                #pragma unroll
                for (int r = 0; r < 4; r++) {
                    float p = __expf(s4[nj][r] * 0.125f);
                    lsum[r] += p;
                    Ph[(w * 16 + quad * 4 + r) * 72 + nj * 16 + l15] = rne_bf16(p);
                }
            }
        }

        bf16x8 ph[2];
        #pragma unroll
        for (int ks = 0; ks < 2; ks++)
            ph[ks] = *(const bf16x8*)&Ph[(w * 16 + l15) * 72 + ks * 32 + quad * 8];
        __builtin_amdgcn_s_setprio(1);
        #pragma unroll
        for (int dt = 0; dt < 4; dt++) {
            int vr = (dt * 16 + l15) * 72 + quad * 8;
            #pragma unroll
            for (int ks = 0; ks < 2; ks++) {
                bf16x8 vv = *(const bf16x8*)&Vs[vr + ks * 32];
                o[dt] = MFMA16(ph[ks], vv, o[dt]);
            }
        }
        __builtin_amdgcn_s_setprio(0);

        if (pf) {
            __syncthreads();   // all waves done reading Ks/Vs
            #pragma unroll
            for (int e = 0; e < 2; e++) {
                int row = e * 32 + sr;
                *(bf16x8*)&Ks[row * 72 + sc] = kreg[e];   // compiler waits vmcnt here
                *(bf16x8*)&Vs[row * 72 + sc] = vreg[e];
            }
            __syncthreads();   // next tile staged
        }
    }

    #pragma unroll
    for (int r = 0; r < 4; r++) {
        lsum[r] += __shfl_xor(lsum[r], 1);
        lsum[r] += __shfl_xor(lsum[r], 2);
        lsum[r] += __shfl_xor(lsum[r], 4);
        lsum[r] += __shfl_xor(lsum[r], 8);
    }

    const float g = gamma[h];
    #pragma unroll
    for (int r = 0; r < 4; r++) {
        const int qrow = q0 + w * 16 + quad * 4 + r;
        const float sc2 = g / lsum[r];
        const size_t base = ((size_t)b * 1024 + qrow) * 1024 + h * 64;
        #pragma unroll
        for (int dt = 0; dt < 4; dt++)
            WSr[base + dt * 16 + l15] = rne_bf16(o[dt][r] * sc2);
    }
}

// ---------------------------------------------------------------------------
extern "C" void kernel_launch(void* const* d_in, const int* in_sizes, int n_in,
                              void* d_out, int out_size, void* d_ws, size_t ws_size,
                              hipStream_t stream) {
    const float* query = (const float*)d_in[0];
    const float* key   = (const float*)d_in[1];
    const float* value = (const float*)d_in[2];
    const int*   mask  = (const int*)d_in[3];
    const float* Wq    = (const float*)d_in[4];
    const float* Wk    = (const float*)d_in[5];
    const float* Wv    = (const float*)d_in[6];
    const float* Wo    = (const float*)d_in[7];
    const float* gamma = (const float*)d_in[8];
    float* out = (float*)d_out;

    unsigned short* u = (unsigned short*)d_ws;
    // 58 MB layout (29M ushorts):
    unsigned short* Xbase = u;          // Xqr, Xkr, Xvr (3 x XP)
    unsigned short* Obase = u + 3 * XP; // Qr, Kr, Vt (3 x XP)
    unsigned short* Wpl   = u + 6 * XP; // Wqh, Wkh, Wvh, Woh, Wol (5 x WP)
    unsigned short* WSr   = Xbase;      // alias: Xqr dead after gemm_proj
    unsigned short* Qr = Obase, *Kr = Obase + XP, *Vt = Obase + 2 * XP;
    unsigned short* Woh = Wpl + 3 * WP, *Wol = Wpl + 4 * WP;

    convert_wx<<<16384, 256, 0, stream>>>(Wq, Wk, Wv, Wo, query, key, value, mask, Wpl, Xbase);

    gemm_proj<<<dim3(8, 32, 3), 256, 0, stream>>>(Xbase, Wpl, mask, Obase);

    attn_mfma<<<dim3(16, 16, 4), 256, 0, stream>>>(Qr, Kr, Vt, mask, gamma, WSr);

    gemm_out2<<<dim3(16, 32), 256, 0, stream>>>(WSr, Woh, Wol, out);
}